// Round 7
// baseline (96.869 us; speedup 1.0000x reference)
//
#include <hip/hip_runtime.h>
#include <stdint.h>
#include <math.h>

#define B_N 512
#define M_N 65536
#define D_N 256
#define C_N 10
#define TEMP_INV 14.285714285714286f   // 1/0.07
#define LOG2E_F 1.4426950408889634f
#define K2C (LOG2E_F * TEMP_INV)       // exp(x/T) = exp2(x*K2C)

typedef __attribute__((ext_vector_type(8))) __bf16 bf16x8;
typedef __attribute__((ext_vector_type(4))) float f32x4;

__device__ __forceinline__ unsigned short f2bf(float f) {
  unsigned int u = __float_as_uint(f);
  return (unsigned short)((u + 0x7FFFu + ((u >> 16) & 1u)) >> 16);  // RNE
}
__device__ __forceinline__ float bf2f(unsigned short s) {
  return __uint_as_float(((unsigned int)s) << 16);
}

// K1: fused normalize. Blocks [0,2048): pro_memory -> bf16 pnb (row-major).
// Blocks [2048,2080): q -> f32 qn + bf16 qnb + qnbF ([it][r][hi][8] fragment
// layout: one A-fragment load = 1KB contiguous). Block 0 inits accumulators.
__global__ __launch_bounds__(256) void k_norm_full(const float* __restrict__ pm,
                                                   const float* __restrict__ q,
                                                   unsigned short* __restrict__ pnb,
                                                   float* __restrict__ qn,
                                                   unsigned short* __restrict__ qnb,
                                                   unsigned short* __restrict__ qnbF,
                                                   float* __restrict__ P,
                                                   int* __restrict__ cnt,
                                                   float* __restrict__ Zt,
                                                   float* __restrict__ Ss,
                                                   float* __restrict__ ns_,
                                                   float* __restrict__ out) {
  const int tid = threadIdx.x, w = tid >> 6, l = tid & 63;
  const int g = l >> 4, qs = l & 15;
  if (blockIdx.x == 0) {
    for (int i = tid; i < C_N * D_N; i += 256) P[i] = 0.f;
    if (tid < C_N) cnt[tid] = 0;
    for (int i = tid; i < B_N; i += 256) { Zt[i] = 0.f; Ss[i] = 0.f; ns_[i] = 0.f; }
    if (tid == 0) out[0] = 0.f;
  }
  if (blockIdx.x < 2048) {
    const int rbase = blockIdx.x * 32 + w * 8;
#pragma unroll
    for (int it = 0; it < 2; ++it) {
      const int r = rbase + it * 4 + g;
      const float* src = pm + (size_t)r * D_N;
      float4 v[4];
#pragma unroll
      for (int c = 0; c < 4; ++c) v[c] = *(const float4*)(src + qs * 4 + c * 64);
      float ss = 0.f;
#pragma unroll
      for (int c = 0; c < 4; ++c)
        ss += v[c].x * v[c].x + v[c].y * v[c].y + v[c].z * v[c].z + v[c].w * v[c].w;
      ss += __shfl_xor(ss, 1, 64);
      ss += __shfl_xor(ss, 2, 64);
      ss += __shfl_xor(ss, 4, 64);
      ss += __shfl_xor(ss, 8, 64);
      const float rv = 1.0f / fmaxf(sqrtf(ss), 1e-8f);
      unsigned short* dst = pnb + (size_t)r * D_N;
#pragma unroll
      for (int c = 0; c < 4; ++c) {
        ushort4 o;
        o.x = f2bf(v[c].x * rv); o.y = f2bf(v[c].y * rv);
        o.z = f2bf(v[c].z * rv); o.w = f2bf(v[c].w * rv);
        *(ushort4*)(dst + qs * 4 + c * 64) = o;
      }
    }
  } else {
    const int r = (blockIdx.x - 2048) * 16 + w * 4 + g;
    const float* src = q + (size_t)r * D_N;
    float4 v[4];
#pragma unroll
    for (int c = 0; c < 4; ++c) v[c] = *(const float4*)(src + qs * 4 + c * 64);
    float ss = 0.f;
#pragma unroll
    for (int c = 0; c < 4; ++c)
      ss += v[c].x * v[c].x + v[c].y * v[c].y + v[c].z * v[c].z + v[c].w * v[c].w;
    ss += __shfl_xor(ss, 1, 64);
    ss += __shfl_xor(ss, 2, 64);
    ss += __shfl_xor(ss, 4, 64);
    ss += __shfl_xor(ss, 8, 64);
    const float rv = 1.0f / fmaxf(sqrtf(ss), 1e-8f);
    float* dstf = qn + (size_t)r * D_N;
    unsigned short* dstb = qnb + (size_t)r * D_N;
#pragma unroll
    for (int c = 0; c < 4; ++c) {
      float4 o4;
      o4.x = v[c].x * rv; o4.y = v[c].y * rv; o4.z = v[c].z * rv; o4.w = v[c].w * rv;
      *(float4*)(dstf + qs * 4 + c * 64) = o4;
      ushort4 o;
      o.x = f2bf(o4.x); o.y = f2bf(o4.y); o.z = f2bf(o4.z); o.w = f2bf(o4.w);
      *(ushort4*)(dstb + qs * 4 + c * 64) = o;
      const int kc = (qs >> 1) + c * 8;          // 16B chunk index (0..31)
      const int itc = kc >> 2, hic = kc & 3;
      *(ushort4*)(qnbF + ((((size_t)itc * 512 + r) * 4 + hic) << 3) + (qs & 1) * 4) = o;
    }
  }
}

// K2 mega-kernel:
//   blocks [0,1024): Z_mem GEMM over 64 m-rows x all 512 q. B reg-staged into
//     LDS at 544B pitch (conflict-free), ONE barrier. A-fragments direct from
//     L2-hot qnbF ([it][r][hi][8]: 1KB contiguous per load). acc[4][4].
//     Z partials -> Zpart[bid][512]; fused per-class dim-sums -> part[bid].
//   blocks [1024,1040): src branch (verified 128x128 core).
__global__ __launch_bounds__(256, 3) void k_mega(const unsigned short* __restrict__ qnb,
                                                 const unsigned short* __restrict__ qnbF,
                                                 const unsigned short* __restrict__ pnb,
                                                 const int* __restrict__ labels,
                                                 const int* __restrict__ pl,
                                                 float* __restrict__ Zt,
                                                 float* __restrict__ Ss,
                                                 float* __restrict__ ns_,
                                                 float* __restrict__ Zpart,
                                                 float* __restrict__ part) {
  __shared__ __align__(16) unsigned char smem[37120];
  const int bid = blockIdx.x;
  const int tid = threadIdx.x, w = tid >> 6, lane = tid & 63;
  const int rsel = lane & 15, hi = lane >> 4;

  if (bid < 1024) {
    // ---------------- Z_mem branch ----------------
    unsigned short* Bs = (unsigned short*)smem;            // 64 rows x 544B pitch
    float* zall = (float*)(smem + 34816);                  // [512]
    int* plL = (int*)(smem + 36864);                       // [64]
    const unsigned short* Bb = pnb + (size_t)bid * 64 * D_N;
    if (tid < 64) plL[tid] = pl[bid * 64 + tid];
    {
      bf16x8 t8[8];
#pragma unroll
      for (int i = 0; i < 8; ++i) {
        const int c = i * 256 + tid;
        t8[i] = *(const bf16x8*)(Bb + (size_t)c * 8);       // linear, coalesced
      }
#pragma unroll
      for (int i = 0; i < 8; ++i) {
        const int c = i * 256 + tid;
        const int r = c >> 5, s = c & 31;
        *(bf16x8*)((char*)Bs + r * 544 + s * 16) = t8[i];   // padded pitch
      }
    }
    __syncthreads();   // the ONLY barrier before the flush

#pragma unroll
    for (int bt = 0; bt < 2; ++bt) {
      f32x4 acc[4][4];
#pragma unroll
      for (int mi = 0; mi < 4; ++mi)
#pragma unroll
        for (int ni = 0; ni < 4; ++ni)
          acc[mi][ni] = (f32x4){0.f, 0.f, 0.f, 0.f};
#pragma unroll
      for (int it = 0; it < 8; ++it) {
        const int kc = it * 4 + hi;                        // k-chunk per quarter
        bf16x8 af[4], bfr[4];
#pragma unroll
        for (int mi = 0; mi < 4; ++mi) {
          const int r = bt * 256 + w * 64 + mi * 16 + rsel;
          af[mi] = *(const bf16x8*)(qnbF + ((((size_t)it * 512 + r) * 4 + hi) << 3));
        }
#pragma unroll
        for (int ni = 0; ni < 4; ++ni) {
          const int rB = ni * 16 + rsel;
          bfr[ni] = *(const bf16x8*)((const char*)Bs + rB * 544 + kc * 16);
        }
#pragma unroll
        for (int mi = 0; mi < 4; ++mi)
#pragma unroll
          for (int ni = 0; ni < 4; ++ni)
            acc[mi][ni] = __builtin_amdgcn_mfma_f32_16x16x32_bf16(af[mi], bfr[ni], acc[mi][ni], 0, 0, 0);
      }
      // epilogue for this q-half: sum exp over this block's 64 m-cols
#pragma unroll
      for (int mi = 0; mi < 4; ++mi) {
        float sv[4] = {0.f, 0.f, 0.f, 0.f};
#pragma unroll
        for (int ni = 0; ni < 4; ++ni)
#pragma unroll
          for (int rg = 0; rg < 4; ++rg)
            sv[rg] += __builtin_amdgcn_exp2f(acc[mi][ni][rg] * K2C);
#pragma unroll
        for (int rg = 0; rg < 4; ++rg) {
          float v = sv[rg];
          v += __shfl_xor(v, 1, 64);
          v += __shfl_xor(v, 2, 64);
          v += __shfl_xor(v, 4, 64);
          v += __shfl_xor(v, 8, 64);
          if (rsel == 0)
            zall[bt * 256 + w * 64 + mi * 16 + hi * 4 + rg] = v;  // owner-unique
        }
      }
    }
    __syncthreads();
    float* zp = Zpart + (size_t)bid * 512;
    for (int i = tid; i < 512; i += 256) zp[i] = zall[i];

    // fused class partial sums from the LDS B-tile (thread = one dim).
    {
      float s0 = 0.f, s1 = 0.f, s2 = 0.f, s3 = 0.f, s4 = 0.f;
      float s5 = 0.f, s6 = 0.f, s7 = 0.f, s8 = 0.f, s9 = 0.f;
#pragma unroll 8
      for (int r = 0; r < 64; ++r) {
        const float v = bf2f(*(const unsigned short*)((const char*)Bs + r * 544 + tid * 2));
        switch (plL[r]) {
          case 0: s0 += v; break;
          case 1: s1 += v; break;
          case 2: s2 += v; break;
          case 3: s3 += v; break;
          case 4: s4 += v; break;
          case 5: s5 += v; break;
          case 6: s6 += v; break;
          case 7: s7 += v; break;
          case 8: s8 += v; break;
          default: s9 += v; break;
        }
      }
      float* dst = part + (size_t)bid * (C_N * D_N) + tid;
      dst[0] = s0; dst[256] = s1; dst[512] = s2; dst[768] = s3; dst[1024] = s4;
      dst[1280] = s5; dst[1536] = s6; dst[1792] = s7; dst[2048] = s8; dst[2304] = s9;
    }
  } else {
    // ---------------- src branch (verified 128x128 core) ----------------
    unsigned short* As = (unsigned short*)smem;            // 128x64
    unsigned short* Bs = (unsigned short*)(smem + 16384);  // 128x64
    int* labR = (int*)(smem + 32768);
    int* labJ = (int*)(smem + 33280);
    float* zr = (float*)(smem + 33792);
    float* sr = (float*)(smem + 34304);
    float* nr = (float*)(smem + 34816);
    const int sb_id = bid - 1024;
    const int bt = sb_id >> 2, jt = sb_id & 3;
    const unsigned short* Ab = qnb + (size_t)(bt * 128) * D_N;
    const unsigned short* Bb = qnb + (size_t)(jt * 128) * D_N;
    if (tid < 128) {
      labR[tid] = labels[bt * 128 + tid];
      labJ[tid] = labels[jt * 128 + tid];
      zr[tid] = 0.f; sr[tid] = 0.f; nr[tid] = 0.f;
    }
    f32x4 acc[4][4];
#pragma unroll
    for (int mi = 0; mi < 4; ++mi)
#pragma unroll
      for (int ni = 0; ni < 4; ++ni)
        acc[mi][ni] = (f32x4){0.f, 0.f, 0.f, 0.f};
    const int wr = w >> 1, wc = w & 1;
    for (int ks = 0; ks < 4; ++ks) {
      const int kk = ks * 64;
#pragma unroll
      for (int i = 0; i < 4; ++i) {
        const int cbase = i * 256 + w * 64;
        const int c = cbase + lane;
        const int r = c >> 3;
        const int ss2 = (c & 7) ^ (r & 7);
        __builtin_amdgcn_global_load_lds(
            (const __attribute__((address_space(1))) void*)(Ab + (size_t)r * D_N + kk + ss2 * 8),
            (__attribute__((address_space(3))) void*)(As + cbase * 8), 16, 0, 0);
        __builtin_amdgcn_global_load_lds(
            (const __attribute__((address_space(1))) void*)(Bb + (size_t)r * D_N + kk + ss2 * 8),
            (__attribute__((address_space(3))) void*)(Bs + cbase * 8), 16, 0, 0);
      }
      __syncthreads();
#pragma unroll
      for (int ksl = 0; ksl < 2; ++ksl) {
        const int sb = ksl * 4 + hi;
        bf16x8 af[4], bfr[4];
#pragma unroll
        for (int mi = 0; mi < 4; ++mi) {
          const int r = wr * 64 + mi * 16 + rsel;
          af[mi] = *(const bf16x8*)((const char*)As + r * 128 + ((sb ^ (r & 7)) * 16));
        }
#pragma unroll
        for (int ni = 0; ni < 4; ++ni) {
          const int r = wc * 64 + ni * 16 + rsel;
          bfr[ni] = *(const bf16x8*)((const char*)Bs + r * 128 + ((sb ^ (r & 7)) * 16));
        }
#pragma unroll
        for (int mi = 0; mi < 4; ++mi)
#pragma unroll
          for (int ni = 0; ni < 4; ++ni)
            acc[mi][ni] = __builtin_amdgcn_mfma_f32_16x16x32_bf16(af[mi], bfr[ni], acc[mi][ni], 0, 0, 0);
      }
      __syncthreads();
    }
#pragma unroll
    for (int mi = 0; mi < 4; ++mi) {
      float zs[4] = {0.f, 0.f, 0.f, 0.f};
      float sv[4] = {0.f, 0.f, 0.f, 0.f};
      float nv[4] = {0.f, 0.f, 0.f, 0.f};
#pragma unroll
      for (int ni = 0; ni < 4; ++ni) {
        const int j_loc = wc * 64 + ni * 16 + rsel;
        const int jg = jt * 128 + j_loc;
        const int lj = labJ[j_loc];
#pragma unroll
        for (int rg_ = 0; rg_ < 4; ++rg_) {
          const int r_loc = wr * 64 + mi * 16 + hi * 4 + rg_;
          const int rg = bt * 128 + r_loc;
          const float lg = acc[mi][ni][rg_] * TEMP_INV - TEMP_INV;
          if (rg != jg) {
            zs[rg_] += __builtin_amdgcn_exp2f(lg * LOG2E_F);
            if (labR[r_loc] == lj) { sv[rg_] += lg; nv[rg_] += 1.f; }
          }
        }
      }
#pragma unroll
      for (int rg_ = 0; rg_ < 4; ++rg_) {
        float z = zs[rg_], s = sv[rg_], n = nv[rg_];
        z += __shfl_xor(z, 1, 64); z += __shfl_xor(z, 2, 64);
        z += __shfl_xor(z, 4, 64); z += __shfl_xor(z, 8, 64);
        s += __shfl_xor(s, 1, 64); s += __shfl_xor(s, 2, 64);
        s += __shfl_xor(s, 4, 64); s += __shfl_xor(s, 8, 64);
        n += __shfl_xor(n, 1, 64); n += __shfl_xor(n, 2, 64);
        n += __shfl_xor(n, 4, 64); n += __shfl_xor(n, 8, 64);
        if (rsel == 0) {
          const int r_loc = wr * 64 + mi * 16 + hi * 4 + rg_;
          atomicAdd(&zr[r_loc], z);
          atomicAdd(&sr[r_loc], s);
          atomicAdd(&nr[r_loc], n);
        }
      }
    }
    __syncthreads();
    if (tid < 128) {
      atomicAdd(&Zt[bt * 128 + tid], zr[tid]);
      atomicAdd(&Ss[bt * 128 + tid], sr[tid]);
      atomicAdd(&ns_[bt * 128 + tid], nr[tid]);
    }
  }
}

// K3: fused reductions. Blocks [0,40): class partials -> P, counts from pl.
// Blocks [40,48): Zpart columns -> Zt (+=, after src atomics are in).
__global__ __launch_bounds__(256) void k_reduce2(const float* __restrict__ part,
                                                 const int* __restrict__ pl,
                                                 const float* __restrict__ Zpart,
                                                 float* __restrict__ P,
                                                 int* __restrict__ cnt,
                                                 float* __restrict__ Zt) {
  const int tid = threadIdx.x, w = tid >> 6, lane = tid & 63;
  if (blockIdx.x < 40) {
    __shared__ int xs[4];
    const int c = blockIdx.x >> 2, q = blockIdx.x & 3;
    float s = 0.f;
#pragma unroll 8
    for (int i = 0; i < 256; ++i)
      s += part[(size_t)(q * 256 + i) * (C_N * D_N) + c * 256 + tid];
    atomicAdd(&P[c * 256 + tid], s);
    int x = 0;
    const int* plq = pl + q * 16384;
#pragma unroll 8
    for (int jj = 0; jj < 64; ++jj)
      x += (plq[jj * 256 + tid] == c) ? 1 : 0;
    x += __shfl_xor(x, 32, 64);
    x += __shfl_xor(x, 16, 64);
    x += __shfl_xor(x, 8, 64);
    x += __shfl_xor(x, 4, 64);
    x += __shfl_xor(x, 2, 64);
    x += __shfl_xor(x, 1, 64);
    if (lane == 0) xs[w] = x;
    __syncthreads();
    if (tid == 0) atomicAdd(&cnt[c], xs[0] + xs[1] + xs[2] + xs[3]);
  } else {
    __shared__ float zl[4][64];
    const int zb = blockIdx.x - 40;
    const int b = zb * 64 + (tid & 63);
    const int s = tid >> 6;
    float acc = 0.f;
#pragma unroll 8
    for (int k = 0; k < 256; ++k)
      acc += Zpart[(size_t)(s * 256 + k) * 512 + b];
    zl[s][tid & 63] = acc;
    __syncthreads();
    if (tid < 64)
      Zt[zb * 64 + tid] += zl[0][tid] + zl[1][tid] + zl[2][tid] + zl[3][tid];
  }
}

// K4: loss. 128 blocks, 1 row per wave.
__global__ __launch_bounds__(256) void k_final(const float* __restrict__ qn,
                                               const int* __restrict__ labels,
                                               const float* __restrict__ P,
                                               const int* __restrict__ cnt,
                                               const float* __restrict__ Zt,
                                               const float* __restrict__ Ss,
                                               const float* __restrict__ ns_,
                                               float* __restrict__ out) {
  __shared__ float partl[4];
  const int tid = threadIdx.x, w = tid >> 6, lane = tid & 63;
  const int b = blockIdx.x * 4 + w;
  const int cls = labels[b];
  const float4 v = *(const float4*)(qn + (size_t)b * D_N + lane * 4);
  const float4 p = *(const float4*)(P + (size_t)cls * D_N + lane * 4);
  float d = v.x * p.x + v.y * p.y + v.z * p.z + v.w * p.w;
  d += __shfl_xor(d, 32, 64);
  d += __shfl_xor(d, 16, 64);
  d += __shfl_xor(d, 8, 64);
  d += __shfl_xor(d, 4, 64);
  d += __shfl_xor(d, 2, 64);
  d += __shfl_xor(d, 1, 64);
  if (lane == 0) {
    const float smem_ = d * TEMP_INV;
    const float ntot = ns_[b] + (float)cnt[cls];
    partl[w] = (Ss[b] + smem_) / ntot - logf(Zt[b]);
  }
  __syncthreads();
  if (tid == 0)
    atomicAdd(out, -(partl[0] + partl[1] + partl[2] + partl[3]) * (1.0f / (float)B_N));
}

extern "C" void kernel_launch(void* const* d_in, const int* in_sizes, int n_in,
                              void* d_out, int out_size, void* d_ws, size_t ws_size,
                              hipStream_t stream) {
  const float* q = (const float*)d_in[0];
  const int* labels = (const int*)d_in[1];
  const float* pm = (const float*)d_in[2];
  const int* pl = (const int*)d_in[3];
  float* out = (float*)d_out;

  char* wsb = (char*)d_ws;
  unsigned short* pnb = (unsigned short*)wsb;              // 33,554,432 B
  float* qn = (float*)(wsb + 33554432);                    // 524,288 B
  unsigned short* qnb = (unsigned short*)(wsb + 34078720); // 262,144 B
  float* P = (float*)(wsb + 34340864);                     // 10,240 B
  int* cnt = (int*)(wsb + 34351104);                       // 64 B
  float* Zt = (float*)(wsb + 34351168);                    // 2,048 B
  float* Ss = (float*)(wsb + 34353216);                    // 2,048 B
  float* ns_ = (float*)(wsb + 34355264);                   // 2,048 B
  float* part = (float*)(wsb + 34357312);                  // 1024*2560*4 = 10,485,760 B
  float* Zpart = (float*)(wsb + 44843072);                 // 1024*512*4 = 2,097,152 B
  unsigned short* qnbF = (unsigned short*)(wsb + 46940224);// 32*512*8*2 = 262,144 B

  k_norm_full<<<2080, 256, 0, stream>>>(pm, q, pnb, qn, qnb, qnbF, P, cnt, Zt, Ss, ns_, out);
  k_mega<<<1040, 256, 0, stream>>>(qnb, qnbF, pnb, labels, pl, Zt, Ss, ns_, Zpart, part);
  k_reduce2<<<48, 256, 0, stream>>>(part, pl, Zpart, P, cnt, Zt);
  k_final<<<128, 256, 0, stream>>>(qn, labels, P, cnt, Zt, Ss, ns_, out);
}

// Round 8
// 86.895 us; speedup vs baseline: 1.1148x; 1.1148x over previous
//
#include <hip/hip_runtime.h>
#include <stdint.h>
#include <math.h>

#define B_N 512
#define M_N 65536
#define D_N 256
#define C_N 10
#define TEMP_INV 14.285714285714286f   // 1/0.07
#define LOG2E_F 1.4426950408889634f
#define K2C (LOG2E_F * TEMP_INV)       // exp(x/T) = exp2(x*K2C)

typedef __attribute__((ext_vector_type(8))) __bf16 bf16x8;
typedef __attribute__((ext_vector_type(4))) float f32x4;

__device__ __forceinline__ unsigned short f2bf(float f) {
  unsigned int u = __float_as_uint(f);
  return (unsigned short)((u + 0x7FFFu + ((u >> 16) & 1u)) >> 16);  // RNE
}
__device__ __forceinline__ float bf2f(unsigned short s) {
  return __uint_as_float(((unsigned int)s) << 16);
}

// K1: fused normalize. Blocks [0,2048): pro_memory -> bf16 pnb (row-major).
// Blocks [2048,2080): q -> f32 qn + bf16 qnb + qnbF ([it][r][hi][8] fragment
// layout: one A-fragment load = 1KB contiguous). Block 0 inits accumulators.
__global__ __launch_bounds__(256) void k_norm_full(const float* __restrict__ pm,
                                                   const float* __restrict__ q,
                                                   unsigned short* __restrict__ pnb,
                                                   float* __restrict__ qn,
                                                   unsigned short* __restrict__ qnb,
                                                   unsigned short* __restrict__ qnbF,
                                                   float* __restrict__ P,
                                                   int* __restrict__ cnt,
                                                   float* __restrict__ Zt,
                                                   float* __restrict__ Ss,
                                                   float* __restrict__ ns_,
                                                   float* __restrict__ out) {
  const int tid = threadIdx.x, w = tid >> 6, l = tid & 63;
  const int g = l >> 4, qs = l & 15;
  if (blockIdx.x == 0) {
    for (int i = tid; i < C_N * D_N; i += 256) P[i] = 0.f;
    if (tid < C_N) cnt[tid] = 0;
    for (int i = tid; i < B_N; i += 256) { Zt[i] = 0.f; Ss[i] = 0.f; ns_[i] = 0.f; }
    if (tid == 0) out[0] = 0.f;
  }
  if (blockIdx.x < 2048) {
    const int rbase = blockIdx.x * 32 + w * 8;
#pragma unroll
    for (int it = 0; it < 2; ++it) {
      const int r = rbase + it * 4 + g;
      const float* src = pm + (size_t)r * D_N;
      float4 v[4];
#pragma unroll
      for (int c = 0; c < 4; ++c) v[c] = *(const float4*)(src + qs * 4 + c * 64);
      float ss = 0.f;
#pragma unroll
      for (int c = 0; c < 4; ++c)
        ss += v[c].x * v[c].x + v[c].y * v[c].y + v[c].z * v[c].z + v[c].w * v[c].w;
      ss += __shfl_xor(ss, 1, 64);
      ss += __shfl_xor(ss, 2, 64);
      ss += __shfl_xor(ss, 4, 64);
      ss += __shfl_xor(ss, 8, 64);
      const float rv = 1.0f / fmaxf(sqrtf(ss), 1e-8f);
      unsigned short* dst = pnb + (size_t)r * D_N;
#pragma unroll
      for (int c = 0; c < 4; ++c) {
        ushort4 o;
        o.x = f2bf(v[c].x * rv); o.y = f2bf(v[c].y * rv);
        o.z = f2bf(v[c].z * rv); o.w = f2bf(v[c].w * rv);
        *(ushort4*)(dst + qs * 4 + c * 64) = o;
      }
    }
  } else {
    const int r = (blockIdx.x - 2048) * 16 + w * 4 + g;
    const float* src = q + (size_t)r * D_N;
    float4 v[4];
#pragma unroll
    for (int c = 0; c < 4; ++c) v[c] = *(const float4*)(src + qs * 4 + c * 64);
    float ss = 0.f;
#pragma unroll
    for (int c = 0; c < 4; ++c)
      ss += v[c].x * v[c].x + v[c].y * v[c].y + v[c].z * v[c].z + v[c].w * v[c].w;
    ss += __shfl_xor(ss, 1, 64);
    ss += __shfl_xor(ss, 2, 64);
    ss += __shfl_xor(ss, 4, 64);
    ss += __shfl_xor(ss, 8, 64);
    const float rv = 1.0f / fmaxf(sqrtf(ss), 1e-8f);
    float* dstf = qn + (size_t)r * D_N;
    unsigned short* dstb = qnb + (size_t)r * D_N;
#pragma unroll
    for (int c = 0; c < 4; ++c) {
      float4 o4;
      o4.x = v[c].x * rv; o4.y = v[c].y * rv; o4.z = v[c].z * rv; o4.w = v[c].w * rv;
      *(float4*)(dstf + qs * 4 + c * 64) = o4;
      ushort4 o;
      o.x = f2bf(o4.x); o.y = f2bf(o4.y); o.z = f2bf(o4.z); o.w = f2bf(o4.w);
      *(ushort4*)(dstb + qs * 4 + c * 64) = o;
      const int kc = (qs >> 1) + c * 8;          // 16B chunk index (0..31)
      const int itc = kc >> 2, hic = kc & 3;
      *(ushort4*)(qnbF + ((((size_t)itc * 512 + r) * 4 + hic) << 3) + (qs & 1) * 4) = o;
    }
  }
}

// K2 mega-kernel:
//   blocks [0,16): src branch (verified 128x128 core) — first, overlaps GEMM.
//   blocks [16,528): Z_mem GEMM, 128 m-rows x all 512 q. B reg-staged into LDS
//     at 544B pitch (conflict-free), ONE barrier. A-fragments direct from
//     qnbF with explicit ping-pong depth-1 prefetch (afA/afB). acc[4][8].
//     Z partials (4 columns) -> Zpart[mt][512]; fused class sums -> part[mt].
__global__ __launch_bounds__(256, 2) void k_mega(const unsigned short* __restrict__ qnb,
                                                 const unsigned short* __restrict__ qnbF,
                                                 const unsigned short* __restrict__ pnb,
                                                 const int* __restrict__ labels,
                                                 const int* __restrict__ pl,
                                                 float* __restrict__ Zt,
                                                 float* __restrict__ Ss,
                                                 float* __restrict__ ns_,
                                                 float* __restrict__ Zpart,
                                                 float* __restrict__ part) {
  __shared__ __align__(16) unsigned char smem[78336];
  const int bid = blockIdx.x;
  const int tid = threadIdx.x, w = tid >> 6, lane = tid & 63;
  const int rsel = lane & 15, hi = lane >> 4;

  if (bid >= 16) {
    // ---------------- Z_mem branch ----------------
    const int mt = bid - 16;                               // 0..511
    unsigned short* Bs = (unsigned short*)smem;            // 128 rows x 544B
    float* zall = (float*)(smem + 69632);                  // [512][4]
    int* plL = (int*)(smem + 77824);                       // [128]
    const unsigned short* Bb = pnb + (size_t)mt * 128 * D_N;
    if (tid < 128) plL[tid] = pl[mt * 128 + tid];
    {
      bf16x8 t8[16];
#pragma unroll
      for (int i = 0; i < 16; ++i) {
        const int c = i * 256 + tid;
        t8[i] = *(const bf16x8*)(Bb + (size_t)c * 8);       // linear, coalesced
      }
#pragma unroll
      for (int i = 0; i < 16; ++i) {
        const int c = i * 256 + tid;
        const int r = c >> 5, s = c & 31;
        *(bf16x8*)((char*)Bs + r * 544 + s * 16) = t8[i];   // padded pitch
      }
    }
    __syncthreads();   // the ONLY barrier

    bf16x8 afA[4], afB[4];
#define LOADA(dst, bt_, it_)                                                   \
    {                                                                          \
      _Pragma("unroll")                                                        \
      for (int mi = 0; mi < 4; ++mi) {                                         \
        const int r_ = (bt_) * 256 + w * 64 + mi * 16 + rsel;                  \
        dst[mi] = *(const bf16x8*)(qnbF + ((((size_t)(it_) * 512 + r_) * 4 + hi) << 3)); \
      }                                                                        \
    }
#define GEMM_IT(it_, CUR, NXT, PBT, PIT, DOPF)                                 \
    {                                                                          \
      if (DOPF) LOADA(NXT, PBT, PIT);                                          \
      bf16x8 bfr[8];                                                           \
      const int kc_ = (it_) * 4 + hi;                                          \
      _Pragma("unroll")                                                        \
      for (int ni = 0; ni < 8; ++ni) {                                         \
        const int rB_ = ni * 16 + rsel;                                        \
        bfr[ni] = *(const bf16x8*)((const char*)Bs + rB_ * 544 + kc_ * 16);    \
      }                                                                        \
      _Pragma("unroll")                                                        \
      for (int mi = 0; mi < 4; ++mi)                                           \
        _Pragma("unroll")                                                      \
        for (int ni = 0; ni < 8; ++ni)                                         \
          acc[mi][ni] = __builtin_amdgcn_mfma_f32_16x16x32_bf16(CUR[mi], bfr[ni], acc[mi][ni], 0, 0, 0); \
    }
#define EPI(bt_)                                                               \
    _Pragma("unroll")                                                          \
    for (int mi = 0; mi < 4; ++mi) {                                           \
      float sv[4] = {0.f, 0.f, 0.f, 0.f};                                      \
      _Pragma("unroll")                                                        \
      for (int ni = 0; ni < 8; ++ni)                                           \
        _Pragma("unroll")                                                      \
        for (int rg = 0; rg < 4; ++rg)                                         \
          sv[rg] += __builtin_amdgcn_exp2f(acc[mi][ni][rg] * K2C);             \
      _Pragma("unroll")                                                        \
      for (int rg = 0; rg < 4; ++rg) {                                         \
        float v_ = sv[rg];                                                     \
        v_ += __shfl_xor(v_, 1, 64);                                           \
        v_ += __shfl_xor(v_, 2, 64);                                           \
        if ((rsel & 3) == 0)                                                   \
          zall[((bt_) * 256 + w * 64 + mi * 16 + hi * 4 + rg) * 4 + (rsel >> 2)] = v_; \
      }                                                                        \
    }

    LOADA(afA, 0, 0);
    {
      f32x4 acc[4][8];
#pragma unroll
      for (int mi = 0; mi < 4; ++mi)
#pragma unroll
        for (int ni = 0; ni < 8; ++ni)
          acc[mi][ni] = (f32x4){0.f, 0.f, 0.f, 0.f};
      GEMM_IT(0, afA, afB, 0, 1, 1)
      GEMM_IT(1, afB, afA, 0, 2, 1)
      GEMM_IT(2, afA, afB, 0, 3, 1)
      GEMM_IT(3, afB, afA, 0, 4, 1)
      GEMM_IT(4, afA, afB, 0, 5, 1)
      GEMM_IT(5, afB, afA, 0, 6, 1)
      GEMM_IT(6, afA, afB, 0, 7, 1)
      GEMM_IT(7, afB, afA, 1, 0, 1)   // prefetch bt1 it0 into afA
      EPI(0)
    }
    {
      f32x4 acc[4][8];
#pragma unroll
      for (int mi = 0; mi < 4; ++mi)
#pragma unroll
        for (int ni = 0; ni < 8; ++ni)
          acc[mi][ni] = (f32x4){0.f, 0.f, 0.f, 0.f};
      GEMM_IT(0, afA, afB, 1, 1, 1)
      GEMM_IT(1, afB, afA, 1, 2, 1)
      GEMM_IT(2, afA, afB, 1, 3, 1)
      GEMM_IT(3, afB, afA, 1, 4, 1)
      GEMM_IT(4, afA, afB, 1, 5, 1)
      GEMM_IT(5, afB, afA, 1, 6, 1)
      GEMM_IT(6, afA, afB, 1, 7, 1)
      GEMM_IT(7, afB, afA, 1, 7, 0)   // no prefetch
      EPI(1)
    }
#undef LOADA
#undef GEMM_IT
#undef EPI
    __syncthreads();
    // flush Z partials (fold the 4 zall columns)
    for (int i = tid; i < 512; i += 256) {
      const f32x4 z4 = *(const f32x4*)&zall[i * 4];
      Zpart[(size_t)mt * 512 + i] = z4[0] + z4[1] + z4[2] + z4[3];
    }
    // fused class partial sums from the LDS B-tile (thread = one dim).
    {
      float s0 = 0.f, s1 = 0.f, s2 = 0.f, s3 = 0.f, s4 = 0.f;
      float s5 = 0.f, s6 = 0.f, s7 = 0.f, s8 = 0.f, s9 = 0.f;
#pragma unroll 8
      for (int r = 0; r < 128; ++r) {
        const float v = bf2f(*(const unsigned short*)((const char*)Bs + r * 544 + tid * 2));
        switch (plL[r]) {
          case 0: s0 += v; break;
          case 1: s1 += v; break;
          case 2: s2 += v; break;
          case 3: s3 += v; break;
          case 4: s4 += v; break;
          case 5: s5 += v; break;
          case 6: s6 += v; break;
          case 7: s7 += v; break;
          case 8: s8 += v; break;
          default: s9 += v; break;
        }
      }
      float* dst = part + (size_t)mt * (C_N * D_N) + tid;
      dst[0] = s0; dst[256] = s1; dst[512] = s2; dst[768] = s3; dst[1024] = s4;
      dst[1280] = s5; dst[1536] = s6; dst[1792] = s7; dst[2048] = s8; dst[2304] = s9;
    }
  } else {
    // ---------------- src branch (verified 128x128 core) ----------------
    unsigned short* As = (unsigned short*)smem;            // 128x64
    unsigned short* Bs = (unsigned short*)(smem + 16384);  // 128x64
    int* labR = (int*)(smem + 32768);
    int* labJ = (int*)(smem + 33280);
    float* zr = (float*)(smem + 33792);
    float* sr = (float*)(smem + 34304);
    float* nr = (float*)(smem + 34816);
    const int sb_id = bid;
    const int bt = sb_id >> 2, jt = sb_id & 3;
    const unsigned short* Ab = qnb + (size_t)(bt * 128) * D_N;
    const unsigned short* Bb = qnb + (size_t)(jt * 128) * D_N;
    if (tid < 128) {
      labR[tid] = labels[bt * 128 + tid];
      labJ[tid] = labels[jt * 128 + tid];
      zr[tid] = 0.f; sr[tid] = 0.f; nr[tid] = 0.f;
    }
    f32x4 acc[4][4];
#pragma unroll
    for (int mi = 0; mi < 4; ++mi)
#pragma unroll
      for (int ni = 0; ni < 4; ++ni)
        acc[mi][ni] = (f32x4){0.f, 0.f, 0.f, 0.f};
    const int wr = w >> 1, wc = w & 1;
    for (int ks = 0; ks < 4; ++ks) {
      const int kk = ks * 64;
#pragma unroll
      for (int i = 0; i < 4; ++i) {
        const int cbase = i * 256 + w * 64;
        const int c = cbase + lane;
        const int r = c >> 3;
        const int ss2 = (c & 7) ^ (r & 7);
        __builtin_amdgcn_global_load_lds(
            (const __attribute__((address_space(1))) void*)(Ab + (size_t)r * D_N + kk + ss2 * 8),
            (__attribute__((address_space(3))) void*)(As + cbase * 8), 16, 0, 0);
        __builtin_amdgcn_global_load_lds(
            (const __attribute__((address_space(1))) void*)(Bb + (size_t)r * D_N + kk + ss2 * 8),
            (__attribute__((address_space(3))) void*)(Bs + cbase * 8), 16, 0, 0);
      }
      __syncthreads();
#pragma unroll
      for (int ksl = 0; ksl < 2; ++ksl) {
        const int sb = ksl * 4 + hi;
        bf16x8 af[4], bfr[4];
#pragma unroll
        for (int mi = 0; mi < 4; ++mi) {
          const int r = wr * 64 + mi * 16 + rsel;
          af[mi] = *(const bf16x8*)((const char*)As + r * 128 + ((sb ^ (r & 7)) * 16));
        }
#pragma unroll
        for (int ni = 0; ni < 4; ++ni) {
          const int r = wc * 64 + ni * 16 + rsel;
          bfr[ni] = *(const bf16x8*)((const char*)Bs + r * 128 + ((sb ^ (r & 7)) * 16));
        }
#pragma unroll
        for (int mi = 0; mi < 4; ++mi)
#pragma unroll
          for (int ni = 0; ni < 4; ++ni)
            acc[mi][ni] = __builtin_amdgcn_mfma_f32_16x16x32_bf16(af[mi], bfr[ni], acc[mi][ni], 0, 0, 0);
      }
      __syncthreads();
    }
#pragma unroll
    for (int mi = 0; mi < 4; ++mi) {
      float zs[4] = {0.f, 0.f, 0.f, 0.f};
      float sv[4] = {0.f, 0.f, 0.f, 0.f};
      float nv[4] = {0.f, 0.f, 0.f, 0.f};
#pragma unroll
      for (int ni = 0; ni < 4; ++ni) {
        const int j_loc = wc * 64 + ni * 16 + rsel;
        const int jg = jt * 128 + j_loc;
        const int lj = labJ[j_loc];
#pragma unroll
        for (int rg_ = 0; rg_ < 4; ++rg_) {
          const int r_loc = wr * 64 + mi * 16 + hi * 4 + rg_;
          const int rg = bt * 128 + r_loc;
          const float lg = acc[mi][ni][rg_] * TEMP_INV - TEMP_INV;
          if (rg != jg) {
            zs[rg_] += __builtin_amdgcn_exp2f(lg * LOG2E_F);
            if (labR[r_loc] == lj) { sv[rg_] += lg; nv[rg_] += 1.f; }
          }
        }
      }
#pragma unroll
      for (int rg_ = 0; rg_ < 4; ++rg_) {
        float z = zs[rg_], s = sv[rg_], n = nv[rg_];
        z += __shfl_xor(z, 1, 64); z += __shfl_xor(z, 2, 64);
        z += __shfl_xor(z, 4, 64); z += __shfl_xor(z, 8, 64);
        s += __shfl_xor(s, 1, 64); s += __shfl_xor(s, 2, 64);
        s += __shfl_xor(s, 4, 64); s += __shfl_xor(s, 8, 64);
        n += __shfl_xor(n, 1, 64); n += __shfl_xor(n, 2, 64);
        n += __shfl_xor(n, 4, 64); n += __shfl_xor(n, 8, 64);
        if (rsel == 0) {
          const int r_loc = wr * 64 + mi * 16 + hi * 4 + rg_;
          atomicAdd(&zr[r_loc], z);
          atomicAdd(&sr[r_loc], s);
          atomicAdd(&nr[r_loc], n);
        }
      }
    }
    __syncthreads();
    if (tid < 128) {
      atomicAdd(&Zt[bt * 128 + tid], zr[tid]);
      atomicAdd(&Ss[bt * 128 + tid], sr[tid]);
      atomicAdd(&ns_[bt * 128 + tid], nr[tid]);
    }
  }
}

// K3: fused reductions. Blocks [0,40): class partials -> P, counts from pl.
// Blocks [40,48): Zpart columns -> Zt (+=, after src atomics are in).
__global__ __launch_bounds__(256) void k_reduce2(const float* __restrict__ part,
                                                 const int* __restrict__ pl,
                                                 const float* __restrict__ Zpart,
                                                 float* __restrict__ P,
                                                 int* __restrict__ cnt,
                                                 float* __restrict__ Zt) {
  const int tid = threadIdx.x, w = tid >> 6, lane = tid & 63;
  if (blockIdx.x < 40) {
    __shared__ int xs[4];
    const int c = blockIdx.x >> 2, q = blockIdx.x & 3;
    float s = 0.f;
#pragma unroll 8
    for (int i = 0; i < 128; ++i)
      s += part[(size_t)(q * 128 + i) * (C_N * D_N) + c * 256 + tid];
    atomicAdd(&P[c * 256 + tid], s);
    int x = 0;
    const int* plq = pl + q * 16384;
#pragma unroll 8
    for (int jj = 0; jj < 64; ++jj)
      x += (plq[jj * 256 + tid] == c) ? 1 : 0;
    x += __shfl_xor(x, 32, 64);
    x += __shfl_xor(x, 16, 64);
    x += __shfl_xor(x, 8, 64);
    x += __shfl_xor(x, 4, 64);
    x += __shfl_xor(x, 2, 64);
    x += __shfl_xor(x, 1, 64);
    if (lane == 0) xs[w] = x;
    __syncthreads();
    if (tid == 0) atomicAdd(&cnt[c], xs[0] + xs[1] + xs[2] + xs[3]);
  } else {
    __shared__ float zl[4][64];
    const int zb = blockIdx.x - 40;
    const int b = zb * 64 + (tid & 63);
    const int s = tid >> 6;
    float acc = 0.f;
#pragma unroll 8
    for (int k = 0; k < 128; ++k)
      acc += Zpart[(size_t)(s * 128 + k) * 512 + b];
    zl[s][tid & 63] = acc;
    __syncthreads();
    if (tid < 64)
      Zt[zb * 64 + tid] += zl[0][tid] + zl[1][tid] + zl[2][tid] + zl[3][tid];
  }
}

// K4: loss. 128 blocks, 1 row per wave.
__global__ __launch_bounds__(256) void k_final(const float* __restrict__ qn,
                                               const int* __restrict__ labels,
                                               const float* __restrict__ P,
                                               const int* __restrict__ cnt,
                                               const float* __restrict__ Zt,
                                               const float* __restrict__ Ss,
                                               const float* __restrict__ ns_,
                                               float* __restrict__ out) {
  __shared__ float partl[4];
  const int tid = threadIdx.x, w = tid >> 6, lane = tid & 63;
  const int b = blockIdx.x * 4 + w;
  const int cls = labels[b];
  const float4 v = *(const float4*)(qn + (size_t)b * D_N + lane * 4);
  const float4 p = *(const float4*)(P + (size_t)cls * D_N + lane * 4);
  float d = v.x * p.x + v.y * p.y + v.z * p.z + v.w * p.w;
  d += __shfl_xor(d, 32, 64);
  d += __shfl_xor(d, 16, 64);
  d += __shfl_xor(d, 8, 64);
  d += __shfl_xor(d, 4, 64);
  d += __shfl_xor(d, 2, 64);
  d += __shfl_xor(d, 1, 64);
  if (lane == 0) {
    const float smem_ = d * TEMP_INV;
    const float ntot = ns_[b] + (float)cnt[cls];
    partl[w] = (Ss[b] + smem_) / ntot - logf(Zt[b]);
  }
  __syncthreads();
  if (tid == 0)
    atomicAdd(out, -(partl[0] + partl[1] + partl[2] + partl[3]) * (1.0f / (float)B_N));
}

extern "C" void kernel_launch(void* const* d_in, const int* in_sizes, int n_in,
                              void* d_out, int out_size, void* d_ws, size_t ws_size,
                              hipStream_t stream) {
  const float* q = (const float*)d_in[0];
  const int* labels = (const int*)d_in[1];
  const float* pm = (const float*)d_in[2];
  const int* pl = (const int*)d_in[3];
  float* out = (float*)d_out;

  char* wsb = (char*)d_ws;
  unsigned short* pnb = (unsigned short*)wsb;              // 33,554,432 B
  float* qn = (float*)(wsb + 33554432);                    // 524,288 B
  unsigned short* qnb = (unsigned short*)(wsb + 34078720); // 262,144 B
  float* P = (float*)(wsb + 34340864);                     // 10,240 B
  int* cnt = (int*)(wsb + 34351104);                       // 64 B
  float* Zt = (float*)(wsb + 34351168);                    // 2,048 B
  float* Ss = (float*)(wsb + 34353216);                    // 2,048 B
  float* ns_ = (float*)(wsb + 34355264);                   // 2,048 B
  float* part = (float*)(wsb + 34357312);                  // 512*2560*4 = 5,242,880 B
  float* Zpart = (float*)(wsb + 39600192);                 // 512*512*4 = 1,048,576 B
  unsigned short* qnbF = (unsigned short*)(wsb + 40648768);// 32*512*8*2 = 262,144 B

  k_norm_full<<<2080, 256, 0, stream>>>(pm, q, pnb, qn, qnb, qnbF, P, cnt, Zt, Ss, ns_, out);
  k_mega<<<528, 256, 0, stream>>>(qnb, qnbF, pnb, labels, pl, Zt, Ss, ns_, Zpart, part);
  k_reduce2<<<48, 256, 0, stream>>>(part, pl, Zpart, P, cnt, Zt);
  k_final<<<128, 256, 0, stream>>>(qn, labels, P, cnt, Zt, Ss, ns_, out);
}